// Round 6
// baseline (2529.551 us; speedup 1.0000x reference)
//
#include <hip/hip_runtime.h>
#include <math.h>

// Problem constants
#define NB   4        // batch
#define NH   16       // heads
#define DHD  64       // head dim
#define SL   2048     // Lq == Lk
#define DM   1024     // model dim
#define TOPK 205      // ceil(2048 * 0.1)

// ws layout (floats):
//  Qh/Ql bf16 [B,H,L,64]   : 4M each @ 0, 4M
//  Kh/Kl bf16 [B,H,L,64]   : 4M each @ 8M, 12M
//  Vth/Vtl bf16 [B,H,64,L] : 4M each @ 16M, 20M   (transposed, tanh applied)
//  P0/P1 fp32 [B,L,D]      : 8M each @ 24M, 32M   (k-split partials of ctx)
//  S [chunk,L,L]           : @ 40M, fp32 scores, overwritten in place by
//                            softmax as bf16 hi(k)|lo(2048+k) per row
#define WS_QH  0
#define WS_QL  4194304
#define WS_KH  8388608
#define WS_KL  12582912
#define WS_VTH 16777216
#define WS_VTL 20971520
#define WS_P0  25165824
#define WS_P1  33554432
#define WS_S   41943040
#define S_PER_BH 4194304   // 2048*2048 floats per (b,h) plane

typedef short bf16x8 __attribute__((ext_vector_type(8)));
typedef float f32x4  __attribute__((ext_vector_type(4)));
typedef unsigned short ushort8 __attribute__((ext_vector_type(8)));

// Round-to-nearest-even float -> bf16 split: x ~= hi + lo, both bf16.
__device__ inline void split2(float x, unsigned short& h, unsigned short& l)
{
    unsigned u = __float_as_uint(x);
    unsigned r = u + 0x7FFF + ((u >> 16) & 1);
    unsigned short hs = (unsigned short)(r >> 16);
    float hf = __uint_as_float((unsigned)hs << 16);
    float lf = x - hf;
    unsigned ul = __float_as_uint(lf);
    unsigned rl = ul + 0x7FFF + ((ul >> 16) & 1);
    h = hs;
    l = (unsigned short)(rl >> 16);
}

__device__ inline float bf2f(unsigned short h) {
    return __uint_as_float((unsigned)h << 16);
}

// ---------------------------------------------------------------------------
// Projection GEMM via split-bf16 MFMA: out = (X [+X2]) @ W^T + bias.
// 128x128 tile, BK=32, 4 waves x (4x4 16x16x32 tiles).
// mode 0: write head-major bf16 hi/lo;  mode 1: tanh + TRANSPOSED bf16 hi/lo
// ([bh,d,l], for av B-operand);  mode 2: plain fp32 [M,N].
// ---------------------------------------------------------------------------
__global__ __launch_bounds__(256) void gemm_proj_mfma(const float* __restrict__ X,
                                                      const float* __restrict__ X2,
                                                      const float* __restrict__ W,
                                                      const float* __restrict__ bias,
                                                      float* __restrict__ outf,
                                                      unsigned short* __restrict__ outh,
                                                      unsigned short* __restrict__ outl,
                                                      int mode)
{
    __shared__ unsigned short Ah[128 * 40];
    __shared__ unsigned short Al[128 * 40];
    __shared__ unsigned short Bh[128 * 40];
    __shared__ unsigned short Bl[128 * 40];

    const int t    = threadIdx.x;
    const int lane = t & 63;
    const int wv   = t >> 6;
    const int wm   = (wv & 1) * 64;
    const int wn   = (wv >> 1) * 64;
    const int n0   = blockIdx.x * 128;
    const int m0   = blockIdx.y * 128;
    const int ra   = t >> 1;
    const int ca   = (t & 1) * 16;

    const float* Xp  = X + (size_t)(m0 + ra) * DM + ca;
    const float* X2p = X2 ? (X2 + (size_t)(m0 + ra) * DM + ca) : nullptr;
    const float* Wp  = W + (size_t)(n0 + ra) * DM + ca;

    f32x4 acc[4][4] = {};
    const int lm   = lane & 15;
    const int koff = (lane >> 4) * 8;

    for (int kb = 0; kb < DM; kb += 32) {
        float4 xv[4], wvv[4];
        #pragma unroll
        for (int q = 0; q < 4; ++q) {
            xv[q]  = *(const float4*)(Xp + kb + q * 4);
            wvv[q] = *(const float4*)(Wp + kb + q * 4);
        }
        if (X2p) {
            #pragma unroll
            for (int q = 0; q < 4; ++q) {
                float4 e = *(const float4*)(X2p + kb + q * 4);
                xv[q].x += e.x; xv[q].y += e.y; xv[q].z += e.z; xv[q].w += e.w;
            }
        }
        __syncthreads();
        ushort8 xh[2], xl[2], wh[2], wl[2];
        #pragma unroll
        for (int g = 0; g < 2; ++g)
            #pragma unroll
            for (int e = 0; e < 8; ++e) {
                unsigned short h_, l_;
                split2(((const float*)xv)[g * 8 + e], h_, l_);
                xh[g][e] = h_; xl[g][e] = l_;
                split2(((const float*)wvv)[g * 8 + e], h_, l_);
                wh[g][e] = h_; wl[g][e] = l_;
            }
        *(ushort8*)&Ah[ra * 40 + ca]     = xh[0];
        *(ushort8*)&Ah[ra * 40 + ca + 8] = xh[1];
        *(ushort8*)&Al[ra * 40 + ca]     = xl[0];
        *(ushort8*)&Al[ra * 40 + ca + 8] = xl[1];
        *(ushort8*)&Bh[ra * 40 + ca]     = wh[0];
        *(ushort8*)&Bh[ra * 40 + ca + 8] = wh[1];
        *(ushort8*)&Bl[ra * 40 + ca]     = wl[0];
        *(ushort8*)&Bl[ra * 40 + ca + 8] = wl[1];
        __syncthreads();
        bf16x8 a_h[4], a_l[4], b_h[4], b_l[4];
        #pragma unroll
        for (int i = 0; i < 4; ++i) {
            int idx = (wm + i * 16 + lm) * 40 + koff;
            a_h[i] = *(const bf16x8*)&Ah[idx];
            a_l[i] = *(const bf16x8*)&Al[idx];
        }
        #pragma unroll
        for (int j = 0; j < 4; ++j) {
            int jdx = (wn + j * 16 + lm) * 40 + koff;
            b_h[j] = *(const bf16x8*)&Bh[jdx];
            b_l[j] = *(const bf16x8*)&Bl[jdx];
        }
        #pragma unroll
        for (int i = 0; i < 4; ++i)
            #pragma unroll
            for (int j = 0; j < 4; ++j) {
                acc[i][j] = __builtin_amdgcn_mfma_f32_16x16x32_bf16(
                    a_h[i], b_h[j], acc[i][j], 0, 0, 0);
                acc[i][j] = __builtin_amdgcn_mfma_f32_16x16x32_bf16(
                    a_h[i], b_l[j], acc[i][j], 0, 0, 0);
                acc[i][j] = __builtin_amdgcn_mfma_f32_16x16x32_bf16(
                    a_l[i], b_h[j], acc[i][j], 0, 0, 0);
            }
    }

    const int rq = (lane >> 4) * 4;
    #pragma unroll
    for (int j = 0; j < 4; ++j) {
        int n = n0 + wn + j * 16 + lm;
        float bb = bias[n];
        #pragma unroll
        for (int i = 0; i < 4; ++i) {
            #pragma unroll
            for (int r = 0; r < 4; ++r) {
                int m = m0 + wm + i * 16 + rq + r;
                float v = acc[i][j][r] + bb;
                if (mode == 2) {
                    outf[(size_t)m * DM + n] = v;
                } else if (mode == 0) {
                    int b = m >> 11, l = m & 2047, hh = n >> 6, d = n & 63;
                    size_t idx = (((size_t)(b * NH + hh)) * SL + l) * DHD + d;
                    unsigned short h_, l_;
                    split2(v, h_, l_);
                    outh[idx] = h_; outl[idx] = l_;
                } else {                       // mode 1: tanh + transpose
                    v = tanhf(v);
                    int b = m >> 11, l = m & 2047, hh = n >> 6, d = n & 63;
                    size_t idx = (((size_t)(b * NH + hh)) * DHD + d) * SL + l;
                    unsigned short h_, l_;
                    split2(v, h_, l_);
                    outh[idx] = h_; outl[idx] = l_;
                }
            }
        }
    }
}

// ---------------------------------------------------------------------------
// Scores via split-bf16 MFMA, fragments straight from global (no LDS).
// S[z,q,k] = 0.25 * Q·K  (masked -> -20000).  grid (16,16,chunk).
// ---------------------------------------------------------------------------
__global__ __launch_bounds__(256) void scores_mfma(const unsigned short* __restrict__ Qh,
                                                   const unsigned short* __restrict__ Ql,
                                                   const unsigned short* __restrict__ Kh,
                                                   const unsigned short* __restrict__ Kl,
                                                   const int* __restrict__ mask,
                                                   float* __restrict__ S,
                                                   int bh0)
{
    const int t    = threadIdx.x;
    const int lane = t & 63;
    const int wv   = t >> 6;
    const int wm   = (wv & 1) * 64;
    const int wn   = (wv >> 1) * 64;
    const int k0   = blockIdx.x * 128;
    const int q0   = blockIdx.y * 128;
    const int z    = blockIdx.z;
    const int bh   = bh0 + z;
    const int lm   = lane & 15;
    const int koff = (lane >> 4) * 8;

    f32x4 acc[4][4] = {};
    const size_t qbase = ((size_t)bh * SL + q0 + wm + lm) * DHD;
    const size_t kbase = ((size_t)bh * SL + k0 + wn + lm) * DHD;

    #pragma unroll
    for (int ds = 0; ds < DHD; ds += 32) {
        bf16x8 a_h[4], a_l[4], b_h[4], b_l[4];
        #pragma unroll
        for (int i = 0; i < 4; ++i) {
            a_h[i] = *(const bf16x8*)(Qh + qbase + (size_t)i * 16 * DHD + ds + koff);
            a_l[i] = *(const bf16x8*)(Ql + qbase + (size_t)i * 16 * DHD + ds + koff);
        }
        #pragma unroll
        for (int j = 0; j < 4; ++j) {
            b_h[j] = *(const bf16x8*)(Kh + kbase + (size_t)j * 16 * DHD + ds + koff);
            b_l[j] = *(const bf16x8*)(Kl + kbase + (size_t)j * 16 * DHD + ds + koff);
        }
        #pragma unroll
        for (int i = 0; i < 4; ++i)
            #pragma unroll
            for (int j = 0; j < 4; ++j) {
                acc[i][j] = __builtin_amdgcn_mfma_f32_16x16x32_bf16(
                    a_h[i], b_h[j], acc[i][j], 0, 0, 0);
                acc[i][j] = __builtin_amdgcn_mfma_f32_16x16x32_bf16(
                    a_h[i], b_l[j], acc[i][j], 0, 0, 0);
                acc[i][j] = __builtin_amdgcn_mfma_f32_16x16x32_bf16(
                    a_l[i], b_h[j], acc[i][j], 0, 0, 0);
            }
    }

    const int b  = bh >> 4;
    const int rq = (lane >> 4) * 4;
    #pragma unroll
    for (int j = 0; j < 4; ++j) {
        int n  = k0 + wn + j * 16 + lm;
        int mk = mask[(size_t)b * SL + n];
        #pragma unroll
        for (int i = 0; i < 4; ++i)
            #pragma unroll
            for (int r = 0; r < 4; ++r) {
                int q = q0 + wm + i * 16 + rq + r;
                S[((size_t)z * SL + q) * SL + n] =
                    mk ? -20000.0f : acc[i][j][r] * 0.25f;
            }
    }
}

// ---------------------------------------------------------------------------
// Softmax + exact top-k (bitwise binary search), then write P back IN PLACE
// as bf16 hi/lo: row ushorts [0..2048) = hi, [2048..4096) = lo.
// One row per wave.
// ---------------------------------------------------------------------------
__global__ __launch_bounds__(256) void softmax_topk(float* __restrict__ S)
{
    const int wave = threadIdx.x >> 6;
    const int lane = threadIdx.x & 63;
    const size_t row = (size_t)blockIdx.x * 4 + wave;
    float4* Sr = (float4*)(S + row * SL);

    float4 v[8];
    #pragma unroll
    for (int i = 0; i < 8; ++i) v[i] = Sr[lane + 64 * i];

    float m = -1e30f;
    #pragma unroll
    for (int i = 0; i < 8; ++i)
        m = fmaxf(m, fmaxf(fmaxf(v[i].x, v[i].y), fmaxf(v[i].z, v[i].w)));
    #pragma unroll
    for (int o = 32; o > 0; o >>= 1) m = fmaxf(m, __shfl_xor(m, o, 64));

    float sum = 0.0f;
    #pragma unroll
    for (int i = 0; i < 8; ++i) {
        v[i].x = __expf(v[i].x - m); v[i].y = __expf(v[i].y - m);
        v[i].z = __expf(v[i].z - m); v[i].w = __expf(v[i].w - m);
        sum += (v[i].x + v[i].y) + (v[i].z + v[i].w);
    }
    #pragma unroll
    for (int o = 32; o > 0; o >>= 1) sum += __shfl_xor(sum, o, 64);
    float inv = 1.0f / sum;
    #pragma unroll
    for (int i = 0; i < 8; ++i) {
        v[i].x *= inv; v[i].y *= inv; v[i].z *= inv; v[i].w *= inv;
    }

    unsigned lo = 0u, hi = __float_as_uint(inv);
    while (lo < hi) {
        unsigned mid = (lo + hi + 1u) >> 1;
        int cnt = 0;
        #pragma unroll
        for (int i = 0; i < 8; ++i) {
            cnt += (__float_as_uint(v[i].x) >= mid);
            cnt += (__float_as_uint(v[i].y) >= mid);
            cnt += (__float_as_uint(v[i].z) >= mid);
            cnt += (__float_as_uint(v[i].w) >= mid);
        }
        #pragma unroll
        for (int o = 32; o > 0; o >>= 1) cnt += __shfl_xor(cnt, o, 64);
        if (cnt >= TOPK) lo = mid; else hi = mid - 1u;
    }

    unsigned short* Sr16 = (unsigned short*)(S + row * SL);
    #pragma unroll
    for (int i = 0; i < 8; ++i) {
        float4 x = v[i];
        x.x = (__float_as_uint(x.x) >= lo) ? x.x : 0.0f;
        x.y = (__float_as_uint(x.y) >= lo) ? x.y : 0.0f;
        x.z = (__float_as_uint(x.z) >= lo) ? x.z : 0.0f;
        x.w = (__float_as_uint(x.w) >= lo) ? x.w : 0.0f;
        unsigned short h0,h1,h2,h3,l0,l1,l2,l3;
        split2(x.x, h0, l0); split2(x.y, h1, l1);
        split2(x.z, h2, l2); split2(x.w, h3, l3);
        int k4 = (lane + 64 * i) * 4;
        *(ushort4*)&Sr16[k4]        = make_ushort4(h0, h1, h2, h3);
        *(ushort4*)&Sr16[2048 + k4] = make_ushort4(l0, l1, l2, l3);
    }
}

// ---------------------------------------------------------------------------
// AV via split-bf16 MFMA, fragments straight from global (no LDS, no barrier).
// Pout[ks][b,q,h*64+d] = (sum_{k in seg} P[z,q,k] * Vt[bh,d,k]) * q_gate
// grid (16 qtiles, 2 ksegs, chunk); partials summed in O-projection staging.
// ---------------------------------------------------------------------------
__global__ __launch_bounds__(256) void av_mfma(const float* __restrict__ S,
                                               const unsigned short* __restrict__ Vth,
                                               const unsigned short* __restrict__ Vtl,
                                               const unsigned short* __restrict__ Qh,
                                               const unsigned short* __restrict__ Ql,
                                               float* __restrict__ Pout,
                                               int bh0)
{
    const int t    = threadIdx.x;
    const int lane = t & 63;
    const int wv   = t >> 6;
    const int wm   = (wv & 1) * 64;   // q offset
    const int wn   = (wv >> 1) * 32;  // d offset
    const int q0   = blockIdx.x * 128;
    const int kseg = blockIdx.y * (SL / 2);
    const int z    = blockIdx.z;
    const int bh   = bh0 + z;
    const int b    = bh >> 4, hh = bh & 15;
    const int lm   = lane & 15;
    const int koff = (lane >> 4) * 8;

    Pout += (size_t)blockIdx.y * ((size_t)NB * SL * DM);

    f32x4 acc[4][2] = {};
    const unsigned short* Pb = (const unsigned short*)(S + (size_t)z * SL * SL);
    size_t prow[4], vrow[2];
    #pragma unroll
    for (int i = 0; i < 4; ++i)
        prow[i] = (size_t)(q0 + wm + i * 16 + lm) * (2 * SL);
    #pragma unroll
    for (int j = 0; j < 2; ++j)
        vrow[j] = ((size_t)bh * DHD + wn + j * 16 + lm) * SL;

    #pragma unroll 2
    for (int k = kseg; k < kseg + SL / 2; k += 32) {
        bf16x8 a_h[4], a_l[4], b_h[2], b_l[2];
        #pragma unroll
        for (int i = 0; i < 4; ++i) {
            a_h[i] = *(const bf16x8*)(Pb + prow[i] + k + koff);
            a_l[i] = *(const bf16x8*)(Pb + prow[i] + SL + k + koff);
        }
        #pragma unroll
        for (int j = 0; j < 2; ++j) {
            b_h[j] = *(const bf16x8*)(Vth + vrow[j] + k + koff);
            b_l[j] = *(const bf16x8*)(Vtl + vrow[j] + k + koff);
        }
        #pragma unroll
        for (int i = 0; i < 4; ++i)
            #pragma unroll
            for (int j = 0; j < 2; ++j) {
                acc[i][j] = __builtin_amdgcn_mfma_f32_16x16x32_bf16(
                    a_h[i], b_h[j], acc[i][j], 0, 0, 0);
                acc[i][j] = __builtin_amdgcn_mfma_f32_16x16x32_bf16(
                    a_h[i], b_l[j], acc[i][j], 0, 0, 0);
                acc[i][j] = __builtin_amdgcn_mfma_f32_16x16x32_bf16(
                    a_l[i], b_h[j], acc[i][j], 0, 0, 0);
            }
    }

    const int rq = (lane >> 4) * 4;
    #pragma unroll
    for (int j = 0; j < 2; ++j) {
        int d = wn + j * 16 + lm;
        #pragma unroll
        for (int i = 0; i < 4; ++i)
            #pragma unroll
            for (int r = 0; r < 4; ++r) {
                int q = q0 + wm + i * 16 + rq + r;
                size_t gidx = ((size_t)bh * SL + q) * DHD + d;
                float g = bf2f(Qh[gidx]) + bf2f(Ql[gidx]);
                Pout[((size_t)b * SL + q) * DM + hh * DHD + d] =
                    acc[i][j][r] * g;
            }
    }
}

// ---------------------------------------------------------------------------
extern "C" void kernel_launch(void* const* d_in, const int* in_sizes, int n_in,
                              void* d_out, int out_size, void* d_ws, size_t ws_size,
                              hipStream_t stream)
{
    const float* q_in = (const float*)d_in[0];
    const float* k_in = (const float*)d_in[1];
    const float* Wq   = (const float*)d_in[2];
    const float* bq   = (const float*)d_in[3];
    const float* Wk   = (const float*)d_in[4];
    const float* bk   = (const float*)d_in[5];
    const float* Wv   = (const float*)d_in[6];
    const float* bv   = (const float*)d_in[7];
    const float* Wo   = (const float*)d_in[8];
    const float* bo   = (const float*)d_in[9];
    const int*   mask = (const int*)d_in[10];   // bool -> int32 per harness
    float* out = (float*)d_out;
    float* ws  = (float*)d_ws;

    unsigned short* Qh16  = (unsigned short*)(ws + WS_QH);
    unsigned short* Ql16  = (unsigned short*)(ws + WS_QL);
    unsigned short* Kh16  = (unsigned short*)(ws + WS_KH);
    unsigned short* Kl16  = (unsigned short*)(ws + WS_KL);
    unsigned short* Vth16 = (unsigned short*)(ws + WS_VTH);
    unsigned short* Vtl16 = (unsigned short*)(ws + WS_VTL);
    float* P0 = ws + WS_P0;
    float* P1 = ws + WS_P1;
    float* S  = ws + WS_S;

    // Adaptive bh-chunking (pure function of ws_size -> graph-capture safe).
    long s_cap_floats = (long)(ws_size / 4) - (long)WS_S;
    int chunk = 64;
    while (chunk > 1 && (long)chunk * (long)S_PER_BH > s_cap_floats) chunk >>= 1;

    dim3 blk(256);
    gemm_proj_mfma<<<dim3(8, 64), blk, 0, stream>>>(q_in, nullptr, Wq, bq,
                                                    nullptr, Qh16, Ql16, 0);
    gemm_proj_mfma<<<dim3(8, 64), blk, 0, stream>>>(k_in, nullptr, Wk, bk,
                                                    nullptr, Kh16, Kl16, 0);
    gemm_proj_mfma<<<dim3(8, 64), blk, 0, stream>>>(k_in, nullptr, Wv, bv,
                                                    nullptr, Vth16, Vtl16, 1);

    for (int bh0 = 0; bh0 < NB * NH; bh0 += chunk) {
        scores_mfma<<<dim3(16, 16, chunk), blk, 0, stream>>>(
            Qh16, Ql16, Kh16, Kl16, mask, S, bh0);
        softmax_topk<<<dim3(chunk * 512), blk, 0, stream>>>(S);
        av_mfma<<<dim3(16, 2, chunk), blk, 0, stream>>>(
            S, Vth16, Vtl16, Qh16, Ql16, P0, bh0);
    }

    gemm_proj_mfma<<<dim3(8, 64), blk, 0, stream>>>(P0, P1, Wo, bo,
                                                    out, nullptr, nullptr, 2);
}